// Round 1
// baseline (400.396 us; speedup 1.0000x reference)
//
#include <hip/hip_runtime.h>
#include <stdint.h>

// Problem constants
#define BB  4
#define SS  2048
#define DD  1024
#define HH  16
#define HDD 64
// M1=8192, N1=3072, K=1024

typedef __attribute__((ext_vector_type(8))) short s16x8;   // 8 bf16 (4 VGPRs)
typedef __attribute__((ext_vector_type(4))) float f32x4;   // MFMA C/D

__device__ inline short f2bf(float f) {
    union { float f; unsigned int u; } v; v.f = f;
    unsigned int r = (v.u + 0x7fffu + ((v.u >> 16) & 1u)) >> 16; // RNE
    return (short)r;
}

#define GLL(gp, lp) __builtin_amdgcn_global_load_lds( \
    (const __attribute__((address_space(1))) void*)(gp), \
    (__attribute__((address_space(3))) void*)(lp), 16, 0, 0)

// ---------------- fp32 -> bf16 cast (n % 8 == 0) ----------------
__global__ void cvt_kernel(const float* __restrict__ src, short* __restrict__ dst, int n) {
    int i = (blockIdx.x * 256 + threadIdx.x) * 8;
    if (i >= n) return;
    const float4* s = (const float4*)(src + i);
    float4 a = s[0], b = s[1];
    s16x8 o;
    o[0]=f2bf(a.x); o[1]=f2bf(a.y); o[2]=f2bf(a.z); o[3]=f2bf(a.w);
    o[4]=f2bf(b.x); o[5]=f2bf(b.y); o[6]=f2bf(b.z); o[7]=f2bf(b.w);
    *(s16x8*)(dst + i) = o;
}

// ---------------- GEMM C = A @ B^T + bias (m97 structure) ----------------
// A: M x K bf16 row-major, Bw: N x K bf16 row-major. M,N % 128 == 0, K % 32 == 0.
// EPI=0: Cf[m*N+n] = acc + bias[n]  (fp32)
// EPI=1: QKV scatter: col -> (sel,h,hd), row -> (b,s); Q,K as (b,h,s,hd); V as (b,h,hd,s) bf16
template<int EPI>
__global__ __launch_bounds__(256)
void gemm_bt(const short* __restrict__ A, const short* __restrict__ Bw,
             const float* __restrict__ bias, float* __restrict__ Cf,
             short* __restrict__ Qo, short* __restrict__ Ko, short* __restrict__ Vo,
             int M, int N, int K)
{
    __shared__ short lsA[128 * 32];
    __shared__ short lsB[128 * 32];
    const int tid  = threadIdx.x;
    const int w    = tid >> 6, lane = tid & 63;
    const int quad = lane >> 4, l15 = lane & 15;
    const int m0 = blockIdx.x * 128, n0 = blockIdx.y * 128;
    const int mw = (w & 1) * 64, nw = (w >> 1) * 64;   // wave's 64x64 quadrant

    f32x4 acc[4][4] = {};

    // staging: wave w loads rows [w*32, w*32+32) of A-tile and B-tile, 2 instrs each
    const int srow = w * 32 + (lane >> 2);
    const int scol = (lane & 3) * 8;
    const short* pA = A + (size_t)(m0 + srow) * K + scol;
    const short* pB = Bw + (size_t)(n0 + srow) * K + scol;
    short* lAbase0 = &lsA[(w * 32) * 32];
    short* lAbase1 = &lsA[(w * 32 + 16) * 32];
    short* lBbase0 = &lsB[(w * 32) * 32];
    short* lBbase1 = &lsB[(w * 32 + 16) * 32];

    for (int kk = 0; kk < K; kk += 32) {
        __syncthreads();
        GLL(pA + kk,            lAbase0);
        GLL(pA + kk + 16 * K,   lAbase1);
        GLL(pB + kk,            lBbase0);
        GLL(pB + kk + 16 * K,   lBbase1);
        asm volatile("s_waitcnt vmcnt(0)" ::: "memory");
        __syncthreads();

        s16x8 af[4], bfr[4];
        for (int t = 0; t < 4; ++t) {
            af[t]  = *(const s16x8*)&lsA[(mw + t * 16 + l15) * 32 + quad * 8];
            bfr[t] = *(const s16x8*)&lsB[(nw + t * 16 + l15) * 32 + quad * 8];
        }
        for (int i = 0; i < 4; ++i)
            for (int j = 0; j < 4; ++j)
                acc[i][j] = __builtin_amdgcn_mfma_f32_16x16x32_bf16(af[i], bfr[j], acc[i][j], 0, 0, 0);
    }

    // epilogue: C/D layout row = quad*4+r, col = lane&15 (within each 16x16 tile)
    if (EPI == 0) {
        for (int i = 0; i < 4; ++i) {
            int row = m0 + mw + i * 16 + quad * 4;
            for (int j = 0; j < 4; ++j) {
                int col = n0 + nw + j * 16 + l15;
                float bv = bias[col];
                for (int r = 0; r < 4; ++r)
                    Cf[(size_t)(row + r) * N + col] = acc[i][j][r] + bv;
            }
        }
    } else {
        for (int i = 0; i < 4; ++i) {
            int row = m0 + mw + i * 16 + quad * 4;
            for (int j = 0; j < 4; ++j) {
                int col = n0 + nw + j * 16 + l15;
                float bv = bias[col];
                int sel = col >> 10, h = (col >> 6) & 15, hd = col & 63;
                for (int r = 0; r < 4; ++r) {
                    int rr = row + r;
                    int b = rr >> 11, s = rr & 2047;
                    short val = f2bf(acc[i][j][r] + bv);
                    if (sel == 0)      Qo[(((size_t)b * HH + h) * SS + s) * HDD + hd] = val;
                    else if (sel == 1) Ko[(((size_t)b * HH + h) * SS + s) * HDD + hd] = val;
                    else               Vo[(((size_t)b * HH + h) * HDD + hd) * SS + s] = val;
                }
            }
        }
    }
}

// ---------------- causal flash attention ----------------
// Q,K: (b,h,s,hd) bf16; V: (b,h,hd,s) bf16; O: (b,s,h*64+hd) bf16
// grid: (S/64, B*H). Block 256: wave w handles q rows [q0+16w, q0+16w+16).
__global__ __launch_bounds__(256)
void attn_kernel(const short* __restrict__ Q, const short* __restrict__ Kb,
                 const short* __restrict__ Vb, const int* __restrict__ mask,
                 short* __restrict__ O)
{
    __shared__ short lsK[128 * 72];        // [key][hd], padded 64->72
    __shared__ short lsV[64 * 136];        // [hd][key], padded 128->136
    __shared__ short lsP[4 * 16 * 136];    // per-wave P, padded
    __shared__ float lsM[128];             // additive key mask

    const int tid  = threadIdx.x;
    const int w    = tid >> 6, lane = tid & 63;
    const int quad = lane >> 4, l15 = lane & 15;
    const int qb = blockIdx.x, bh = blockIdx.y;
    const int b = bh >> 4;
    const int q0 = qb * 64;
    const size_t baseQK = (size_t)bh * SS * HDD;
    const size_t baseV  = (size_t)bh * HDD * SS;

    // Q fragments: A-layout m=lane&15, k=quad*8+j
    const int qrow = q0 + w * 16 + l15;
    s16x8 aq[2];
    for (int ks = 0; ks < 2; ++ks)
        aq[ks] = *(const s16x8*)(Q + baseQK + (size_t)qrow * HDD + ks * 32 + quad * 8);

    float m_r[4], l_r[4];
    f32x4 o_acc[4] = {};
    for (int r = 0; r < 4; ++r) { m_r[r] = -1e30f; l_r[r] = 0.f; }

    const int n_tiles = q0 / 128 + 1;
    short* lsPw = &lsP[w * 16 * 136];

    for (int kt = 0; kt < n_tiles; ++kt) {
        const int kv0 = kt * 128;
        __syncthreads();
        // stage K tile: 128 rows x 64 el -> lsK padded
        for (int i = 0; i < 4; ++i) {
            int ch = tid + i * 256;
            int row = ch >> 3, cs = (ch & 7) * 8;
            s16x8 v = *(const s16x8*)(Kb + baseQK + (size_t)(kv0 + row) * HDD + cs);
            *(s16x8*)&lsK[row * 72 + cs] = v;
        }
        // stage V^T tile: 64 rows(hd) x 128 el(key) -> lsV padded
        for (int i = 0; i < 4; ++i) {
            int ch = tid + i * 256;
            int row = ch >> 4, cs = (ch & 15) * 8;
            s16x8 v = *(const s16x8*)(Vb + baseV + (size_t)row * SS + kv0 + cs);
            *(s16x8*)&lsV[row * 136 + cs] = v;
        }
        if (tid < 128) lsM[tid] = (mask[b * SS + kv0 + tid] != 0) ? 0.f : -1e30f;
        __syncthreads();

        // S = Q K^T
        f32x4 sv[8];
        for (int nt = 0; nt < 8; ++nt) {
            f32x4 s = {};
            for (int ks = 0; ks < 2; ++ks) {
                s16x8 kf = *(const s16x8*)&lsK[(nt * 16 + l15) * 72 + ks * 32 + quad * 8];
                s = __builtin_amdgcn_mfma_f32_16x16x32_bf16(aq[ks], kf, s, 0, 0, 0);
            }
            sv[nt] = s;
        }
        // scale + causal + key mask
        const int rowg0 = q0 + w * 16 + quad * 4;
        for (int nt = 0; nt < 8; ++nt) {
            int colg = kv0 + nt * 16 + l15;
            float madd = lsM[nt * 16 + l15];
            for (int r = 0; r < 4; ++r) {
                float scv = sv[nt][r] * 0.125f + madd;
                if (colg > rowg0 + r) scv = -1e30f;
                sv[nt][r] = scv;
            }
        }
        // online softmax (rows live in 16-lane groups: shfl_xor 1,2,4,8)
        float alpha[4];
        for (int r = 0; r < 4; ++r) {
            float rm = sv[0][r];
            for (int nt = 1; nt < 8; ++nt) rm = fmaxf(rm, sv[nt][r]);
            rm = fmaxf(rm, __shfl_xor(rm, 1));
            rm = fmaxf(rm, __shfl_xor(rm, 2));
            rm = fmaxf(rm, __shfl_xor(rm, 4));
            rm = fmaxf(rm, __shfl_xor(rm, 8));
            float nm = fmaxf(m_r[r], rm);
            alpha[r] = __expf(m_r[r] - nm);
            m_r[r] = nm;
            float rs = 0.f;
            for (int nt = 0; nt < 8; ++nt) {
                float p = __expf(sv[nt][r] - nm);
                sv[nt][r] = p;
                rs += p;
            }
            rs += __shfl_xor(rs, 1);
            rs += __shfl_xor(rs, 2);
            rs += __shfl_xor(rs, 4);
            rs += __shfl_xor(rs, 8);
            l_r[r] = l_r[r] * alpha[r] + rs;
        }
        for (int ht = 0; ht < 4; ++ht)
            for (int r = 0; r < 4; ++r)
                o_acc[ht][r] *= alpha[r];

        // P: C-layout -> A-layout via per-wave LDS roundtrip
        for (int nt = 0; nt < 8; ++nt)
            for (int r = 0; r < 4; ++r)
                lsPw[(quad * 4 + r) * 136 + nt * 16 + l15] = f2bf(sv[nt][r]);
        asm volatile("s_waitcnt lgkmcnt(0)" ::: "memory");

        // O += P V
        for (int k2 = 0; k2 < 4; ++k2) {
            s16x8 ap = *(const s16x8*)&lsPw[l15 * 136 + k2 * 32 + quad * 8];
            for (int ht = 0; ht < 4; ++ht) {
                s16x8 vf = *(const s16x8*)&lsV[(ht * 16 + l15) * 136 + k2 * 32 + quad * 8];
                o_acc[ht] = __builtin_amdgcn_mfma_f32_16x16x32_bf16(ap, vf, o_acc[ht], 0, 0, 0);
            }
        }
    }

    // epilogue: O/(l) -> (b, s, h*64+hd) bf16
    const int hcol = (bh & 15) * HDD;
    for (int r = 0; r < 4; ++r) {
        float inv = 1.0f / l_r[r];
        int srow = q0 + w * 16 + quad * 4 + r;
        size_t base = ((size_t)b * SS + srow) * DD + hcol;
        for (int ht = 0; ht < 4; ++ht)
            O[base + ht * 16 + l15] = f2bf(o_acc[ht][r] * inv);
    }
}

// ---------------- launch ----------------
extern "C" void kernel_launch(void* const* d_in, const int* in_sizes, int n_in,
                              void* d_out, int out_size, void* d_ws, size_t ws_size,
                              hipStream_t stream) {
    const float* x     = (const float*)d_in[0];
    const int*   mask  = (const int*)d_in[1];
    const float* qkv_w = (const float*)d_in[2];
    const float* qkv_b = (const float*)d_in[3];
    const float* out_w = (const float*)d_in[4];
    const float* out_b = (const float*)d_in[5];
    float* out = (float*)d_out;

    const size_t M1 = (size_t)BB * SS;       // 8192
    short* ws  = (short*)d_ws;
    short* xb  = ws;                          // 8M el
    short* qwb = xb  + M1 * DD;               // 3M el
    short* owb = qwb + (size_t)3 * DD * DD;   // 1M el
    short* Qb  = owb + (size_t)DD * DD;       // 8M el
    short* Kb  = Qb  + M1 * DD;
    short* Vb  = Kb  + M1 * DD;
    short* Ob  = Vb  + M1 * DD;

    cvt_kernel<<<(int)(M1 * DD / 8 / 256), 256, 0, stream>>>(x, xb, (int)(M1 * DD));
    cvt_kernel<<<3 * DD * DD / 8 / 256, 256, 0, stream>>>(qkv_w, qwb, 3 * DD * DD);
    cvt_kernel<<<DD * DD / 8 / 256, 256, 0, stream>>>(out_w, owb, DD * DD);

    gemm_bt<1><<<dim3(64, 24), 256, 0, stream>>>(xb, qwb, qkv_b, nullptr,
                                                 Qb, Kb, Vb, 8192, 3072, 1024);
    attn_kernel<<<dim3(SS / 64, BB * HH), 256, 0, stream>>>(Qb, Kb, Vb, mask, Ob);
    gemm_bt<0><<<dim3(64, 8), 256, 0, stream>>>(Ob, owb, out_b, out,
                                                nullptr, nullptr, nullptr, 8192, 1024, 1024);
}

// Round 2
// 324.201 us; speedup vs baseline: 1.2350x; 1.2350x over previous
//
#include <hip/hip_runtime.h>
#include <stdint.h>
#include <type_traits>

// Problem constants
#define BB  4
#define SS  2048
#define DD  1024
#define HH  16
#define HDD 64

typedef __attribute__((ext_vector_type(8))) short s16x8;   // 8 bf16 (4 VGPRs)
typedef __attribute__((ext_vector_type(4))) float f32x4;   // MFMA C/D

__device__ inline short f2bf(float f) {
    union { float f; unsigned int u; } v; v.f = f;
    unsigned int r = (v.u + 0x7fffu + ((v.u >> 16) & 1u)) >> 16; // RNE
    return (short)r;
}

#define GLL(gp, lp) __builtin_amdgcn_global_load_lds( \
    (const __attribute__((address_space(1))) void*)(gp), \
    (__attribute__((address_space(3))) void*)(lp), 16, 0, 0)

// ---------------- fp32 -> bf16 cast (n % 8 == 0) ----------------
__global__ void cvt_kernel(const float* __restrict__ src, short* __restrict__ dst, int n) {
    int i = (blockIdx.x * 256 + threadIdx.x) * 8;
    if (i >= n) return;
    const float4* s = (const float4*)(src + i);
    float4 a = s[0], b = s[1];
    s16x8 o;
    o[0]=f2bf(a.x); o[1]=f2bf(a.y); o[2]=f2bf(a.z); o[3]=f2bf(a.w);
    o[4]=f2bf(b.x); o[5]=f2bf(b.y); o[6]=f2bf(b.z); o[7]=f2bf(b.w);
    *(s16x8*)(dst + i) = o;
}

// ---------------- GEMM C = A @ B^T + bias (m97 structure) ----------------
template<int EPI>
__global__ __launch_bounds__(256)
void gemm_bt(const short* __restrict__ A, const short* __restrict__ Bw,
             const float* __restrict__ bias, float* __restrict__ Cf,
             short* __restrict__ Qo, short* __restrict__ Ko, short* __restrict__ Vo,
             int M, int N, int K)
{
    __shared__ short lsA[128 * 32];
    __shared__ short lsB[128 * 32];
    const int tid  = threadIdx.x;
    const int w    = tid >> 6, lane = tid & 63;
    const int quad = lane >> 4, l15 = lane & 15;
    const int m0 = blockIdx.x * 128, n0 = blockIdx.y * 128;
    const int mw = (w & 1) * 64, nw = (w >> 1) * 64;

    f32x4 acc[4][4] = {};

    const int srow = w * 32 + (lane >> 2);
    const int scol = (lane & 3) * 8;
    const short* pA = A + (size_t)(m0 + srow) * K + scol;
    const short* pB = Bw + (size_t)(n0 + srow) * K + scol;
    short* lAbase0 = &lsA[(w * 32) * 32];
    short* lAbase1 = &lsA[(w * 32 + 16) * 32];
    short* lBbase0 = &lsB[(w * 32) * 32];
    short* lBbase1 = &lsB[(w * 32 + 16) * 32];

    for (int kk = 0; kk < K; kk += 32) {
        __syncthreads();
        GLL(pA + kk,            lAbase0);
        GLL(pA + kk + 16 * K,   lAbase1);
        GLL(pB + kk,            lBbase0);
        GLL(pB + kk + 16 * K,   lBbase1);
        asm volatile("s_waitcnt vmcnt(0)" ::: "memory");
        __syncthreads();

        s16x8 af[4], bfr[4];
        for (int t = 0; t < 4; ++t) {
            af[t]  = *(const s16x8*)&lsA[(mw + t * 16 + l15) * 32 + quad * 8];
            bfr[t] = *(const s16x8*)&lsB[(nw + t * 16 + l15) * 32 + quad * 8];
        }
        for (int i = 0; i < 4; ++i)
            for (int j = 0; j < 4; ++j)
                acc[i][j] = __builtin_amdgcn_mfma_f32_16x16x32_bf16(af[i], bfr[j], acc[i][j], 0, 0, 0);
    }

    if (EPI == 0) {
        for (int i = 0; i < 4; ++i) {
            int row = m0 + mw + i * 16 + quad * 4;
            for (int j = 0; j < 4; ++j) {
                int col = n0 + nw + j * 16 + l15;
                float bv = bias[col];
                for (int r = 0; r < 4; ++r)
                    Cf[(size_t)(row + r) * N + col] = acc[i][j][r] + bv;
            }
        }
    } else {
        for (int i = 0; i < 4; ++i) {
            int row = m0 + mw + i * 16 + quad * 4;
            for (int j = 0; j < 4; ++j) {
                int col = n0 + nw + j * 16 + l15;
                float bv = bias[col];
                int sel = col >> 10, h = (col >> 6) & 15, hd = col & 63;
                for (int r = 0; r < 4; ++r) {
                    int rr = row + r;
                    int b = rr >> 11, s = rr & 2047;
                    short val = f2bf(acc[i][j][r] + bv);
                    if (sel == 0)      Qo[(((size_t)b * HH + h) * SS + s) * HDD + hd] = val;
                    else if (sel == 1) Ko[(((size_t)b * HH + h) * SS + s) * HDD + hd] = val;
                    else               Vo[(((size_t)b * HH + h) * HDD + hd) * SS + s] = val;
                }
            }
        }
    }
}

// ---------------- causal flash attention ----------------
// Q,K: (b,h,s,hd) bf16; V: (b,h,hd,s) bf16; O: (b,s,h*64+hd) bf16
// grid: (16, B*H). Block t-loop handles q-tiles {31-bx, bx} (balanced: 17 tile-units each).
// LDS 36352 B -> 4 blocks/CU. P buffer aliases lsK (K dead after QK^T; extra barrier).
__global__ __launch_bounds__(256, 4)
void attn_kernel(const short* __restrict__ Q, const short* __restrict__ Kb,
                 const short* __restrict__ Vb, const int* __restrict__ mask,
                 short* __restrict__ O)
{
    __shared__ short lsK[128 * 72];        // [key][hd] pad 64->72; reused for P (per-wave 16x136)
    __shared__ short lsV[64 * 136];        // [hd][key] pad 128->136
    __shared__ float lsM[128];

    const int tid  = threadIdx.x;
    const int w    = tid >> 6, lane = tid & 63;
    const int quad = lane >> 4, l15 = lane & 15;
    const int bx = blockIdx.x, bh = blockIdx.y;
    const int b = bh >> 4;
    const size_t baseQK = (size_t)bh * SS * HDD;
    const size_t baseV  = (size_t)bh * HDD * SS;
    short* lsPw = &lsK[w * 16 * 136];
    const float SC = 0.18033688f;          // (1/8) * log2(e)

    for (int t = 0; t < 2; ++t) {
        const int qb = t ? bx : (31 - bx);  // heavy tile first
        const int q0 = qb * 64;
        const int qrow = q0 + w * 16 + l15;
        const int rowg0 = q0 + w * 16 + quad * 4;

        s16x8 aq[2];
        for (int ks = 0; ks < 2; ++ks)
            aq[ks] = *(const s16x8*)(Q + baseQK + (size_t)qrow * HDD + ks * 32 + quad * 8);

        float m_r[4], l_r[4];
        f32x4 o_acc[4] = {};
        for (int r = 0; r < 4; ++r) { m_r[r] = -1e30f; l_r[r] = 0.f; }

        auto tile = [&](auto NTC, auto CC, int kv0) {
            constexpr int NT     = decltype(NTC)::value;   // key-tiles of 16 (4 or 8)
            constexpr bool CAUS  = decltype(CC)::value;
            __syncthreads();                                // prev PV reads done
            // stage K: NT*16 rows x 64 hd
            for (int i = 0; i < NT / 2; ++i) {
                int ch = tid + i * 256;
                int row = ch >> 3, cs = (ch & 7) * 8;
                *(s16x8*)&lsK[row * 72 + cs] =
                    *(const s16x8*)(Kb + baseQK + (size_t)(kv0 + row) * HDD + cs);
            }
            // stage V^T: 64 hd x NT*16 keys
            if constexpr (NT == 8) {
                for (int i = 0; i < 4; ++i) {
                    int ch = tid + i * 256;
                    int row = ch >> 4, cs = (ch & 15) * 8;
                    *(s16x8*)&lsV[row * 136 + cs] =
                        *(const s16x8*)(Vb + baseV + (size_t)row * SS + kv0 + cs);
                }
            } else {
                for (int i = 0; i < 2; ++i) {
                    int ch = tid + i * 256;
                    int row = ch >> 3, cs = (ch & 7) * 8;
                    *(s16x8*)&lsV[row * 136 + cs] =
                        *(const s16x8*)(Vb + baseV + (size_t)row * SS + kv0 + cs);
                }
            }
            if (tid < NT * 16) lsM[tid] = (mask[b * SS + kv0 + tid] != 0) ? 0.f : -1e30f;
            __syncthreads();

            // S = Q K^T  (scaled into log2 domain)
            f32x4 sv[NT];
            for (int nt = 0; nt < NT; ++nt) {
                f32x4 s = {};
                for (int ks = 0; ks < 2; ++ks) {
                    s16x8 kf = *(const s16x8*)&lsK[(nt * 16 + l15) * 72 + ks * 32 + quad * 8];
                    s = __builtin_amdgcn_mfma_f32_16x16x32_bf16(aq[ks], kf, s, 0, 0, 0);
                }
                sv[nt] = s;
            }
            for (int nt = 0; nt < NT; ++nt) {
                int colg = kv0 + nt * 16 + l15;
                float madd = lsM[nt * 16 + l15];
                for (int r = 0; r < 4; ++r) {
                    float scv = sv[nt][r] * SC + madd;
                    if (CAUS && colg > rowg0 + r) scv = -1e30f;
                    sv[nt][r] = scv;
                }
            }
            // online softmax (rows in 16-lane groups)
            float alpha[4];
            for (int r = 0; r < 4; ++r) {
                float rm = sv[0][r];
                for (int nt = 1; nt < NT; ++nt) rm = fmaxf(rm, sv[nt][r]);
                rm = fmaxf(rm, __shfl_xor(rm, 1));
                rm = fmaxf(rm, __shfl_xor(rm, 2));
                rm = fmaxf(rm, __shfl_xor(rm, 4));
                rm = fmaxf(rm, __shfl_xor(rm, 8));
                float nm = fmaxf(m_r[r], rm);
                alpha[r] = __builtin_amdgcn_exp2f(m_r[r] - nm);
                m_r[r] = nm;
                float rs = 0.f;
                for (int nt = 0; nt < NT; ++nt) {
                    float p = __builtin_amdgcn_exp2f(sv[nt][r] - nm);
                    sv[nt][r] = p;
                    rs += p;
                }
                rs += __shfl_xor(rs, 1);
                rs += __shfl_xor(rs, 2);
                rs += __shfl_xor(rs, 4);
                rs += __shfl_xor(rs, 8);
                l_r[r] = l_r[r] * alpha[r] + rs;
            }
            for (int ht = 0; ht < 4; ++ht)
                for (int r = 0; r < 4; ++r)
                    o_acc[ht][r] *= alpha[r];

            __syncthreads();   // all waves done reading lsK as K -> safe to write P
            for (int nt = 0; nt < NT; ++nt)
                for (int r = 0; r < 4; ++r)
                    lsPw[(quad * 4 + r) * 136 + nt * 16 + l15] = f2bf(sv[nt][r]);
            asm volatile("s_waitcnt lgkmcnt(0)" ::: "memory");

            // O += P V
            for (int k2 = 0; k2 < NT / 2; ++k2) {
                s16x8 ap = *(const s16x8*)&lsPw[l15 * 136 + k2 * 32 + quad * 8];
                for (int ht = 0; ht < 4; ++ht) {
                    s16x8 vf = *(const s16x8*)&lsV[(ht * 16 + l15) * 136 + k2 * 32 + quad * 8];
                    o_acc[ht] = __builtin_amdgcn_mfma_f32_16x16x32_bf16(ap, vf, o_acc[ht], 0, 0, 0);
                }
            }
        };

        const int nfull = q0 / 128;   // full, purely-below-diagonal tiles
        for (int kt = 0; kt < nfull; ++kt)
            tile(std::integral_constant<int, 8>{}, std::false_type{}, kt * 128);
        if (qb & 1) tile(std::integral_constant<int, 8>{}, std::true_type{}, nfull * 128);
        else        tile(std::integral_constant<int, 4>{}, std::true_type{}, nfull * 128);

        // epilogue: O/l -> (b, s, h*64+hd) bf16
        const int hcol = (bh & 15) * HDD;
        for (int r = 0; r < 4; ++r) {
            float inv = 1.0f / l_r[r];
            int srow = q0 + w * 16 + quad * 4 + r;
            size_t base = ((size_t)b * SS + srow) * DD + hcol;
            for (int ht = 0; ht < 4; ++ht)
                O[base + ht * 16 + l15] = f2bf(o_acc[ht][r] * inv);
        }
    }
}

// ---------------- launch ----------------
extern "C" void kernel_launch(void* const* d_in, const int* in_sizes, int n_in,
                              void* d_out, int out_size, void* d_ws, size_t ws_size,
                              hipStream_t stream) {
    const float* x     = (const float*)d_in[0];
    const int*   mask  = (const int*)d_in[1];
    const float* qkv_w = (const float*)d_in[2];
    const float* qkv_b = (const float*)d_in[3];
    const float* out_w = (const float*)d_in[4];
    const float* out_b = (const float*)d_in[5];
    float* out = (float*)d_out;

    const size_t M1 = (size_t)BB * SS;       // 8192
    short* ws  = (short*)d_ws;
    short* xb  = ws;
    short* qwb = xb  + M1 * DD;
    short* owb = qwb + (size_t)3 * DD * DD;
    short* Qb  = owb + (size_t)DD * DD;
    short* Kb  = Qb  + M1 * DD;
    short* Vb  = Kb  + M1 * DD;
    short* Ob  = Vb  + M1 * DD;

    cvt_kernel<<<(int)(M1 * DD / 8 / 256), 256, 0, stream>>>(x, xb, (int)(M1 * DD));
    cvt_kernel<<<3 * DD * DD / 8 / 256, 256, 0, stream>>>(qkv_w, qwb, 3 * DD * DD);
    cvt_kernel<<<DD * DD / 8 / 256, 256, 0, stream>>>(out_w, owb, DD * DD);

    gemm_bt<1><<<dim3(64, 24), 256, 0, stream>>>(xb, qwb, qkv_b, nullptr,
                                                 Qb, Kb, Vb, 8192, 3072, 1024);
    attn_kernel<<<dim3(16, BB * HH), 256, 0, stream>>>(Qb, Kb, Vb, mask, Ob);
    gemm_bt<0><<<dim3(64, 8), 256, 0, stream>>>(Ob, owb, out_b, out,
                                                nullptr, nullptr, nullptr, 8192, 1024, 1024);
}